// Round 12
// baseline (1174.325 us; speedup 1.0000x reference)
//
#include <hip/hip_runtime.h>

#define EPSBN 1e-5f

typedef __attribute__((ext_vector_type(8))) __bf16 bf16x8;
typedef __attribute__((ext_vector_type(4))) float f32x4;
typedef __attribute__((ext_vector_type(8))) unsigned short us8;

__device__ inline unsigned short f2bf(float f) {
  __bf16 h = (__bf16)f;
  return __builtin_bit_cast(unsigned short, h);
}
__device__ inline float bf2f(unsigned short u) {
  __bf16 h = __builtin_bit_cast(__bf16, u);
  return (float)h;
}

// ---- last-block BN finalize (threadfence reduction). All threads call uniformly. ----
__device__ inline void bn_finalize_tail(float* acc, int* cnt, int nblk, int NCH,
    const float* __restrict__ gamma, const float* __restrict__ beta,
    float* __restrict__ sc, float* __restrict__ sh, float invN, int tid) {
  __syncthreads();                       // all this block's atomicAdds issued & drained
  __shared__ int lastFlag;
  if (tid == 0) {
    __threadfence();
    lastFlag = (atomicAdd(cnt, 1) == nblk - 1) ? 1 : 0;
  }
  __syncthreads();
  if (lastFlag) {
    __threadfence();
    for (int ch = tid; ch < NCH; ch += 256) {
      float s1 = __hip_atomic_load(acc + ch,        __ATOMIC_RELAXED, __HIP_MEMORY_SCOPE_AGENT);
      float s2 = __hip_atomic_load(acc + NCH + ch,  __ATOMIC_RELAXED, __HIP_MEMORY_SCOPE_AGENT);
      float mean = s1 * invN;
      float var  = s2 * invN - mean * mean;
      float s = gamma[ch] * rsqrtf(var + EPSBN);
      sc[ch] = s;
      sh[ch] = beta[ch] - mean * s;
    }
  }
}

// ---------------- merged setup: weight converts (bf16) + adjacency ----------------
__device__ inline void cvt_cw_seg(const float* w, unsigned short* o, int lidx) {
  o[lidx] = f2bf(w[lidx]);
}
__device__ inline void cvt_tw_seg(const float* w, unsigned short* o, int lidx) {
  int oo = lidx / 384;
  int r = lidx - oo*384;
  int tap = r >> 7, c = r & 127;
  o[lidx] = f2bf(w[(oo*128 + c)*3 + tap]);
}
__global__ __launch_bounds__(256) void k_setup(
    const float* __restrict__ nv1, const float* __restrict__ nv2,
    float* __restrict__ A, float* __restrict__ sA,
    int* __restrict__ cntA, int* __restrict__ lvA, float* __restrict__ lvalA,
    const float* __restrict__ d1g, const float* __restrict__ d1t,
    const float* __restrict__ d2g, const float* __restrict__ d2t,
    unsigned short* __restrict__ O,
    const float* __restrict__ s1p, const float* __restrict__ s1t,
    const float* __restrict__ s2p, const float* __restrict__ s2t,
    unsigned short* __restrict__ S)
{
  int b = blockIdx.x, tid = threadIdx.x;
  if (b < 512) {
    if (b < 64)        cvt_cw_seg(d1g, O,          b*256 + tid);
    else if (b < 256)  cvt_tw_seg(d1t, O + 16384, (b-64)*256 + tid);
    else if (b < 320)  cvt_cw_seg(d2g, O + 65536, (b-256)*256 + tid);
    else               cvt_tw_seg(d2t, O + 81920, (b-320)*256 + tid);
    return;
  }
  if (b < 6784) {
    int sb = b - 512;
    if (sb < 64)        cvt_cw_seg(s1p, S,           sb*256 + tid);
    else if (sb < 3136) cvt_tw_seg(s1t, S + 16384,  (sb-64)*256 + tid);
    else if (sb < 3200) cvt_cw_seg(s2p, S + 802816, (sb-3136)*256 + tid);
    else                cvt_tw_seg(s2t, S + 819200, (sb-3200)*256 + tid);
    return;
  }
  // ---- adjacency (single block) ----
  __shared__ float M[16][16];
  int i = tid >> 4, j = tid & 15;
  float acc = 0.f;
  #pragma unroll
  for (int k = 0; k < 64; ++k) acc += nv1[i*64+k] * nv2[k*16+j];
  M[i][j] = fmaxf(acc, 0.f);
  __syncthreads();
  if (tid < 16) {
    float m = -1e30f;
    for (int c = 0; c < 16; ++c) m = fmaxf(m, M[tid][c]);
    float e[16]; float s = 0.f;
    for (int c = 0; c < 16; ++c) { e[c] = expf(M[tid][c] - m); s += e[c]; }
    float inv = 1.f / s;
    float t1 = -1e30f, t2 = -1e30f;
    for (int c = 0; c < 16; ++c) {
      float a = e[c] * inv; e[c] = a;
      if (a > t1) { t2 = t1; t1 = a; }
      else if (a > t2) t2 = a;
    }
    for (int c = 0; c < 16; ++c) {
      bool keep = (e[c] > (1.0f/16.0f)) && (e[c] > t2);
      M[tid][c] = keep ? e[c] : 0.f;
    }
  }
  __syncthreads();
  A[tid] = M[tid>>4][tid&15];
  if (tid < 16) {           // tid = w (column)
    float s = 0.f;
    int cnt = 0;
    for (int v = 0; v < 16; ++v) {
      float a = M[v][tid];
      s += a;
      if (a != 0.f) { lvA[tid*16 + cnt] = v; lvalA[tid*16 + cnt] = a; ++cnt; }
    }
    sA[tid] = s;
    cntA[tid] = cnt;
  }
}

// ---------------- x -> xB (pos-major bf16) + xS (static-layout bf16), one pass ----------------
__global__ __launch_bounds__(256) void k_xcvt(const float* __restrict__ x,
                                              unsigned short* __restrict__ xB,
                                              unsigned short* __restrict__ xS) {
  __shared__ float tl[64*128];
  int b = blockIdx.x; int n = b >> 6; int t0q = b & 63;
  int tid = threadIdx.x;
  const float* xb = x + (long)n*524288 + t0q*64;
  for (int idx = tid; idx < 2048; idx += 256) {
    int c = idx >> 4, q = idx & 15;
    float4 v = *(const float4*)(xb + (long)c*4096 + q*4);
    int cb = c >> 2, cl = c & 3;
    #pragma unroll
    for (int j = 0; j < 4; ++j)
      tl[(4*q+j)*128 + (((cb ^ q) & 31) << 2) + cl] = ((const float*)&v)[j];
  }
  __syncthreads();
  for (int idx = tid; idx < 1024; idx += 256) {
    int pos = idx >> 4, c8 = (idx & 15) << 3;
    int cb0 = c8 >> 2, cb1 = cb0 + 1, qp = pos >> 2;
    f32x4 v0 = *(const f32x4*)&tl[pos*128 + (((cb0 ^ qp) & 31) << 2)];
    f32x4 v1 = *(const f32x4*)&tl[pos*128 + (((cb1 ^ qp) & 31) << 2)];
    us8 pk;
    pk[0]=f2bf(v0.x); pk[1]=f2bf(v0.y); pk[2]=f2bf(v0.z); pk[3]=f2bf(v0.w);
    pk[4]=f2bf(v1.x); pk[5]=f2bf(v1.y); pk[6]=f2bf(v1.z); pk[7]=f2bf(v1.w);
    *(us8*)(xB + ((long)n*4096 + t0q*64 + pos)*128 + c8) = pk;
    int vv = pos & 15, tt = pos >> 4;
    *(us8*)(xS + ((long)(n*16+vv)*256 + t0q*4 + tt)*128 + c8) = pk;
  }
}

// ========== fused: sparse-agg(xB) gather -> MFMA gconv -> z1 + BN stats (in-kernel finalize) ==========
__global__ __launch_bounds__(256) void k_aggGconv(
    const unsigned short* __restrict__ xB,
    const int* __restrict__ cntA, const int* __restrict__ lvA, const float* __restrict__ lvalA,
    const unsigned short* __restrict__ Wb,
    unsigned short* __restrict__ out,
    const float* __restrict__ gb, const float* __restrict__ sAv,
    float* __restrict__ acc_g, int* __restrict__ cnt_g,
    const float* __restrict__ gamma, const float* __restrict__ beta,
    float* __restrict__ scO, float* __restrict__ shO, float invN)
{
  __shared__ __align__(16) unsigned short Th[64*128];
  __shared__ int cntS[16];
  __shared__ int lvS[256];
  __shared__ float lvalS[256];
  int b = blockIdx.x; int n = b >> 6; int off = (b & 63) << 6;
  int tid = threadIdx.x;
  if (tid < 16) cntS[tid] = cntA[tid];
  lvS[tid] = lvA[tid];
  lvalS[tid] = lvalA[tid];
  __syncthreads();
  const unsigned short* xbase = xB + ((long)n*4096 + off)*128;
  for (int idx = tid; idx < 1024; idx += 256) {
    int pos = idx >> 4, c8 = (idx & 15) << 3;
    int tt = pos >> 4, w = pos & 15;
    float s[8];
    #pragma unroll
    for (int k = 0; k < 8; ++k) s[k] = 0.f;
    int cw = cntS[w];
    for (int j = 0; j < cw; ++j) {
      int p = tt*16 + lvS[w*16 + j];
      float a = lvalS[w*16 + j];
      us8 raw = *(const us8*)(xbase + (long)p*128 + c8);
      #pragma unroll
      for (int k = 0; k < 8; ++k) s[k] += a * bf2f(raw[k]);
    }
    us8 pk;
    #pragma unroll
    for (int k = 0; k < 8; ++k) pk[k] = f2bf(s[k]);
    int byteoff = (pos << 8) + (c8 << 1);
    byteoff ^= ((pos & 7) << 4);
    *(us8*)((char*)Th + byteoff) = pk;
  }
  __syncthreads();
  int wv = tid >> 6, lane = tid & 63, l15 = lane & 15, lhi = lane >> 4;
  int o0 = wv << 5;
  f32x4 zz = {0.f,0.f,0.f,0.f};
  f32x4 acc[2][4];
  #pragma unroll
  for (int i = 0; i < 2; ++i)
    #pragma unroll
    for (int q = 0; q < 4; ++q) acc[i][q] = zz;
  const unsigned short* wr0 = Wb + (long)(o0 + l15)*128 + lhi*8;
  const unsigned short* wr1 = wr0 + 16*128;
  #pragma unroll
  for (int kk = 0; kk < 4; ++kk) {
    int kc = kk*32 + lhi*8;
    bf16x8 a0 = *(const bf16x8*)(wr0 + kk*32);
    bf16x8 a1 = *(const bf16x8*)(wr1 + kk*32);
    #pragma unroll
    for (int pf = 0; pf < 4; ++pf) {
      int row = pf*16 + l15;
      int byteoff = (row << 8) + (kc << 1);
      byteoff ^= ((row & 7) << 4);
      bf16x8 bh = *(const bf16x8*)((const char*)Th + byteoff);
      acc[0][pf] = __builtin_amdgcn_mfma_f32_16x16x32_bf16(a0, bh, acc[0][pf], 0, 0, 0);
      acc[1][pf] = __builtin_amdgcn_mfma_f32_16x16x32_bf16(a1, bh, acc[1][pf], 0, 0, 0);
    }
  }
  float s1a[2][4], s2a[2][4];
  #pragma unroll
  for (int i = 0; i < 2; ++i)
    #pragma unroll
    for (int j = 0; j < 4; ++j) { s1a[i][j] = 0.f; s2a[i][j] = 0.f; }
  unsigned short* og = out + ((long)n*4096 + off)*128;
  #pragma unroll
  for (int of = 0; of < 2; ++of) {
    int oc = o0 + of*16 + lhi*4;
    #pragma unroll
    for (int pf = 0; pf < 4; ++pf) {
      int pos = pf*16 + l15;
      f32x4 r = acc[of][pf];
      float s = sAv[l15];
      r.x += gb[oc+0]*s; r.y += gb[oc+1]*s;
      r.z += gb[oc+2]*s; r.w += gb[oc+3]*s;
      ushort4 pk;
      pk.x = f2bf(r.x); pk.y = f2bf(r.y); pk.z = f2bf(r.z); pk.w = f2bf(r.w);
      *(ushort4*)(og + (long)pos*128 + oc) = pk;
      #pragma unroll
      for (int j = 0; j < 4; ++j) { s1a[of][j] += r[j]; s2a[of][j] += r[j]*r[j]; }
    }
  }
  #pragma unroll
  for (int of = 0; of < 2; ++of)
    #pragma unroll
    for (int j = 0; j < 4; ++j) {
      float a = s1a[of][j], b2 = s2a[of][j];
      #pragma unroll
      for (int m = 1; m < 16; m <<= 1) { a += __shfl_xor(a, m); b2 += __shfl_xor(b2, m); }
      s1a[of][j] = a; s2a[of][j] = b2;
    }
  if (l15 == 0) {
    #pragma unroll
    for (int of = 0; of < 2; ++of)
      #pragma unroll
      for (int j = 0; j < 4; ++j) {
        int ch = o0 + of*16 + lhi*4 + j;
        atomicAdd(acc_g + ch, s1a[of][j]);
        atomicAdd(acc_g + 128 + ch, s2a[of][j]);
      }
  }
  bn_finalize_tail(acc_g, cnt_g, gridDim.x, 128, gamma, beta, scO, shO, invN, tid);
}

// ========== fused: r2=relu(bn(z2)+xB) -> bf16; sparse-agg; gconv2 -> z3 + BN stats ==========
__global__ __launch_bounds__(256) void k_combineAggGconv(
    const unsigned short* __restrict__ z, const unsigned short* __restrict__ xB,
    const int* __restrict__ cntA, const int* __restrict__ lvA, const float* __restrict__ lvalA,
    const float* __restrict__ sc, const float* __restrict__ sh,
    const unsigned short* __restrict__ Wb,
    unsigned short* __restrict__ r2, unsigned short* __restrict__ out,
    const float* __restrict__ gb, const float* __restrict__ sAv,
    float* __restrict__ acc_g, int* __restrict__ cnt_g,
    const float* __restrict__ gamma, const float* __restrict__ beta,
    float* __restrict__ scO, float* __restrict__ shO, float invN)
{
  __shared__ __align__(16) unsigned short rl[64*128];
  __shared__ __align__(16) unsigned short Th[64*128];
  __shared__ int cntS[16];
  __shared__ int lvS[256];
  __shared__ float lvalS[256];
  int b = blockIdx.x;
  int tid = threadIdx.x;
  if (tid < 16) cntS[tid] = cntA[tid];
  lvS[tid] = lvA[tid];
  lvalS[tid] = lvalA[tid];
  long zbase = (long)b * 8192;
  for (int idx = tid; idx < 1024; idx += 256) {
    int pos = idx >> 4, c8 = (idx & 15) << 3;
    us8 zr = *(const us8*)(z  + zbase + (long)pos*128 + c8);
    us8 xr = *(const us8*)(xB + zbase + (long)pos*128 + c8);
    us8 pr;
    #pragma unroll
    for (int k = 0; k < 8; ++k) {
      int cc = c8 + k;
      float v = bf2f(zr[k]) * sc[cc] + sh[cc] + bf2f(xr[k]);
      pr[k] = f2bf(fmaxf(v, 0.f));
    }
    *(us8*)(rl + pos*128 + c8) = pr;
    *(us8*)(r2 + zbase + (long)pos*128 + c8) = pr;
  }
  __syncthreads();
  for (int idx = tid; idx < 1024; idx += 256) {
    int pos = idx >> 4, c8 = (idx & 15) << 3;
    int tt = pos >> 4, w = pos & 15;
    float s[8];
    #pragma unroll
    for (int k = 0; k < 8; ++k) s[k] = 0.f;
    int cw = cntS[w];
    for (int j = 0; j < cw; ++j) {
      int p = tt*16 + lvS[w*16 + j];
      float a = lvalS[w*16 + j];
      us8 raw = *(const us8*)(rl + p*128 + c8);
      #pragma unroll
      for (int k = 0; k < 8; ++k) s[k] += a * bf2f(raw[k]);
    }
    us8 pk;
    #pragma unroll
    for (int k = 0; k < 8; ++k) pk[k] = f2bf(s[k]);
    int byteoff = (pos << 8) + (c8 << 1);
    byteoff ^= ((pos & 7) << 4);
    *(us8*)((char*)Th + byteoff) = pk;
  }
  __syncthreads();
  int wv = tid >> 6, lane = tid & 63, l15 = lane & 15, lhi = lane >> 4;
  int o0 = wv << 5;
  f32x4 zz = {0.f,0.f,0.f,0.f};
  f32x4 acc[2][4];
  #pragma unroll
  for (int i = 0; i < 2; ++i)
    #pragma unroll
    for (int q = 0; q < 4; ++q) acc[i][q] = zz;
  const unsigned short* wr0 = Wb + (long)(o0 + l15)*128 + lhi*8;
  const unsigned short* wr1 = wr0 + 16*128;
  #pragma unroll
  for (int kk = 0; kk < 4; ++kk) {
    int kc = kk*32 + lhi*8;
    bf16x8 a0 = *(const bf16x8*)(wr0 + kk*32);
    bf16x8 a1 = *(const bf16x8*)(wr1 + kk*32);
    #pragma unroll
    for (int pf = 0; pf < 4; ++pf) {
      int row = pf*16 + l15;
      int byteoff = (row << 8) + (kc << 1);
      byteoff ^= ((row & 7) << 4);
      bf16x8 bh = *(const bf16x8*)((const char*)Th + byteoff);
      acc[0][pf] = __builtin_amdgcn_mfma_f32_16x16x32_bf16(a0, bh, acc[0][pf], 0, 0, 0);
      acc[1][pf] = __builtin_amdgcn_mfma_f32_16x16x32_bf16(a1, bh, acc[1][pf], 0, 0, 0);
    }
  }
  float s1a[2][4], s2a[2][4];
  #pragma unroll
  for (int i = 0; i < 2; ++i)
    #pragma unroll
    for (int j = 0; j < 4; ++j) { s1a[i][j] = 0.f; s2a[i][j] = 0.f; }
  unsigned short* og = out + zbase;
  #pragma unroll
  for (int of = 0; of < 2; ++of) {
    int oc = o0 + of*16 + lhi*4;
    #pragma unroll
    for (int pf = 0; pf < 4; ++pf) {
      int pos = pf*16 + l15;
      f32x4 r = acc[of][pf];
      float s = sAv[l15];
      r.x += gb[oc+0]*s; r.y += gb[oc+1]*s;
      r.z += gb[oc+2]*s; r.w += gb[oc+3]*s;
      ushort4 pk;
      pk.x = f2bf(r.x); pk.y = f2bf(r.y); pk.z = f2bf(r.z); pk.w = f2bf(r.w);
      *(ushort4*)(og + (long)pos*128 + oc) = pk;
      #pragma unroll
      for (int j = 0; j < 4; ++j) { s1a[of][j] += r[j]; s2a[of][j] += r[j]*r[j]; }
    }
  }
  #pragma unroll
  for (int of = 0; of < 2; ++of)
    #pragma unroll
    for (int j = 0; j < 4; ++j) {
      float a = s1a[of][j], b2 = s2a[of][j];
      #pragma unroll
      for (int m = 1; m < 16; m <<= 1) { a += __shfl_xor(a, m); b2 += __shfl_xor(b2, m); }
      s1a[of][j] = a; s2a[of][j] = b2;
    }
  if (l15 == 0) {
    #pragma unroll
    for (int of = 0; of < 2; ++of)
      #pragma unroll
      for (int j = 0; j < 4; ++j) {
        int ch = o0 + of*16 + lhi*4 + j;
        atomicAdd(acc_g + ch, s1a[of][j]);
        atomicAdd(acc_g + 128 + ch, s2a[of][j]);
      }
  }
  bn_finalize_tail(acc_g, cnt_g, gridDim.x, 128, gamma, beta, scO, shO, invN, tid);
}

// ================= MFMA conv, bf16 in/out, coalesced stores, in-kernel BN finalize =================
// BNMODE: 1 = 128-channel stats, 2 = 2048-channel (grouped by v = g&15)
template<int POSB, int HALO, int TAPS, int GROUPED_W, int IN_BN, int GROUPED_BN, int RELU_IN, int BNMODE>
__global__ __launch_bounds__(256) void k_conv(
    const unsigned short* __restrict__ in, const unsigned short* __restrict__ Wb,
    unsigned short* __restrict__ out, int L,
    const float* __restrict__ isc, const float* __restrict__ ish,
    float* __restrict__ acc_g, int* __restrict__ cnt_g,
    const float* __restrict__ gamma, const float* __restrict__ beta,
    float* __restrict__ scO, float* __restrict__ shO, float invN)
{
  constexpr int TW = POSB + 2*HALO;
  constexpr int PF = POSB / 16;
  constexpr int KT = TAPS*128;
  constexpr int NCH = (BNMODE == 2) ? 2048 : 128;
  __shared__ __align__(16) unsigned short Th[TW*128];
  int tid = threadIdx.x;
  int bpg = L / POSB;
  int g = blockIdx.x / bpg;
  int pos0 = (blockIdx.x - g*bpg) * POSB;
  const unsigned short* ing = in + (long)g*L*128;

  int cbase = (IN_BN && GROUPED_BN) ? ((g & 15) << 7) : 0;
  for (int idx = tid; idx < TW*16; idx += 256) {
    int row = idx >> 4;
    int c8 = (idx & 15) << 3;
    int gp = pos0 + row - HALO;
    us8 h = (us8)0;
    if (gp >= 0 && gp < L) {
      us8 raw = *(const us8*)(ing + (long)gp*128 + c8);
      if (IN_BN) {
        #pragma unroll
        for (int j = 0; j < 8; ++j) {
          int ci = cbase + c8 + j;
          float v = bf2f(raw[j]) * isc[ci] + ish[ci];
          if (RELU_IN) v = fmaxf(v, 0.f);
          h[j] = f2bf(v);
        }
      } else {
        h = raw;
      }
    }
    int byteoff = (row << 8) + (c8 << 1);
    byteoff ^= ((row & 7) << 4);
    *(us8*)((char*)Th + byteoff) = h;
  }
  __syncthreads();

  int wv = tid >> 6, lane = tid & 63, l15 = lane & 15, lhi = lane >> 4;
  int o0 = wv << 5;

  f32x4 zz = {0.f,0.f,0.f,0.f};
  f32x4 acc[2][PF];
  #pragma unroll
  for (int i = 0; i < 2; ++i)
    #pragma unroll
    for (int q = 0; q < PF; ++q) acc[i][q] = zz;

  const unsigned short* Wg = Wb + (GROUPED_W ? (long)(g & 15)*128*KT : 0);
  const unsigned short* wr0 = Wg + (long)(o0 + l15)*KT + lhi*8;
  const unsigned short* wr1 = wr0 + 16*KT;

  #pragma unroll
  for (int tap = 0; tap < TAPS; ++tap) {
    #pragma unroll
    for (int kk = 0; kk < 4; ++kk) {
      int kc = kk*32 + lhi*8;
      bf16x8 a0 = *(const bf16x8*)(wr0 + tap*128 + kk*32);
      bf16x8 a1 = *(const bf16x8*)(wr1 + tap*128 + kk*32);
      #pragma unroll
      for (int pf = 0; pf < PF; ++pf) {
        int row = pf*16 + l15 + tap*HALO;
        int byteoff = (row << 8) + (kc << 1);
        byteoff ^= ((row & 7) << 4);
        bf16x8 bh = *(const bf16x8*)((const char*)Th + byteoff);
        acc[0][pf] = __builtin_amdgcn_mfma_f32_16x16x32_bf16(a0, bh, acc[0][pf], 0, 0, 0);
        acc[1][pf] = __builtin_amdgcn_mfma_f32_16x16x32_bf16(a1, bh, acc[1][pf], 0, 0, 0);
      }
    }
  }

  // BN partial sums -> global atomics
  float s1a[2][4], s2a[2][4];
  #pragma unroll
  for (int i = 0; i < 2; ++i)
    #pragma unroll
    for (int j = 0; j < 4; ++j) { s1a[i][j] = 0.f; s2a[i][j] = 0.f; }
  #pragma unroll
  for (int of = 0; of < 2; ++of)
    #pragma unroll
    for (int pf = 0; pf < PF; ++pf) {
      f32x4 r = acc[of][pf];
      #pragma unroll
      for (int j = 0; j < 4; ++j) { s1a[of][j] += r[j]; s2a[of][j] += r[j]*r[j]; }
    }
  #pragma unroll
  for (int of = 0; of < 2; ++of)
    #pragma unroll
    for (int j = 0; j < 4; ++j) {
      float a = s1a[of][j], b2 = s2a[of][j];
      #pragma unroll
      for (int m = 1; m < 16; m <<= 1) { a += __shfl_xor(a, m); b2 += __shfl_xor(b2, m); }
      s1a[of][j] = a; s2a[of][j] = b2;
    }
  int chbase = (BNMODE == 2) ? ((g & 15) << 7) : 0;
  if (l15 == 0) {
    #pragma unroll
    for (int of = 0; of < 2; ++of)
      #pragma unroll
      for (int j = 0; j < 4; ++j) {
        int ch = chbase + o0 + of*16 + lhi*4 + j;
        atomicAdd(acc_g + ch, s1a[of][j]);
        atomicAdd(acc_g + NCH + ch, s2a[of][j]);
      }
  }

  // output tile -> Th (swizzled) -> coalesced global store
  __syncthreads();
  #pragma unroll
  for (int of = 0; of < 2; ++of) {
    int oc = o0 + of*16 + lhi*4;
    #pragma unroll
    for (int pf = 0; pf < PF; ++pf) {
      int pos = pf*16 + l15;
      f32x4 r = acc[of][pf];
      ushort4 pk;
      pk.x = f2bf(r.x); pk.y = f2bf(r.y); pk.z = f2bf(r.z); pk.w = f2bf(r.w);
      int byteoff = (pos << 8) + (oc << 1);
      byteoff ^= ((pos & 7) << 4);
      *(ushort4*)((char*)Th + byteoff) = pk;
    }
  }
  __syncthreads();
  unsigned short* og = out + ((long)g*L + pos0)*128;
  for (int idx = tid; idx < POSB*16; idx += 256) {
    int row = idx >> 4, c8 = (idx & 15) << 3;
    int byteoff = (row << 8) + (c8 << 1);
    byteoff ^= ((row & 7) << 4);
    us8 v = *(const us8*)((const char*)Th + byteoff);
    *(us8*)(og + (long)row*128 + c8) = v;
  }

  bn_finalize_tail(acc_g, cnt_g, gridDim.x, NCH, gamma, beta, scO, shO, invN, tid);
}

// ---------------- dynamic tail: out[n,c,v] = max_t relu(bn(z)+r2), bf16 inputs ----------------
__global__ __launch_bounds__(256) void k_maxdyn(
    const unsigned short* __restrict__ z, const unsigned short* __restrict__ res,
    const float* __restrict__ sc, const float* __restrict__ sh,
    float* __restrict__ outp)
{
  int b = blockIdx.x; int n = b >> 4, v = b & 15;
  int tid = threadIdx.x; int c = tid & 127, h = tid >> 7;
  const unsigned short* zb = z   + ((long)n*4096 + v)*128 + c;
  const unsigned short* rb = res + ((long)n*4096 + v)*128 + c;
  float s = sc[c], bb = sh[c];
  float m = 0.f;
  for (int t = h; t < 256; t += 2) {
    float val = bf2f(zb[(long)t*2048]) * s + bb + bf2f(rb[(long)t*2048]);
    m = fmaxf(m, val);
  }
  __shared__ float red[256];
  red[tid] = m;
  __syncthreads();
  if (tid < 128)
    outp[(long)n*4096 + c*32 + v] = fmaxf(fmaxf(red[tid], red[tid+128]), 0.f);
}

// ---------------- static tail: out[n,c,16+v] = max_s bn(z[(n,v)][s][c]), bf16 ----------------
__global__ __launch_bounds__(256) void k_maxstat(
    const unsigned short* __restrict__ z,
    const float* __restrict__ sc, const float* __restrict__ sh,
    float* __restrict__ outp)
{
  int b = blockIdx.x; int n = b >> 4, v = b & 15;
  int tid = threadIdx.x; int c = tid & 127, h = tid >> 7;
  const unsigned short* zb = z + (long)b*256*128 + c;
  float s = sc[v*128 + c], bb = sh[v*128 + c];
  float m = -1e30f;
  for (int t = h; t < 256; t += 2)
    m = fmaxf(m, bf2f(zb[t*128]) * s + bb);
  __shared__ float red[256];
  red[tid] = m;
  __syncthreads();
  if (tid < 128)
    outp[(long)n*4096 + c*32 + 16 + v] = fmaxf(red[tid], red[tid+128]);
}

extern "C" void kernel_launch(void* const* d_in, const int* in_sizes, int n_in,
                              void* d_out, int out_size, void* d_ws, size_t ws_size,
                              hipStream_t stream) {
  (void)in_sizes; (void)n_in; (void)out_size; (void)ws_size;
  const float* x     = (const float*)d_in[0];
  const float* nv1   = (const float*)d_in[1];
  const float* nv2   = (const float*)d_in[2];
  const float* d1gw  = (const float*)d_in[3];
  const float* d1gb  = (const float*)d_in[4];
  const float* d1b1g = (const float*)d_in[5];
  const float* d1b1b = (const float*)d_in[6];
  const float* d1tw  = (const float*)d_in[7];
  const float* d1b2g = (const float*)d_in[9];
  const float* d1b2b = (const float*)d_in[10];
  const float* d2gw  = (const float*)d_in[11];
  const float* d2gb  = (const float*)d_in[12];
  const float* d2b1g = (const float*)d_in[13];
  const float* d2b1b = (const float*)d_in[14];
  const float* d2tw  = (const float*)d_in[15];
  const float* d2b2g = (const float*)d_in[17];
  const float* d2b2b = (const float*)d_in[18];
  const float* s1pw  = (const float*)d_in[19];
  const float* s1pg  = (const float*)d_in[20];
  const float* s1pb  = (const float*)d_in[21];
  const float* s1tw  = (const float*)d_in[22];
  const float* s1tg  = (const float*)d_in[23];
  const float* s1tb  = (const float*)d_in[24];
  const float* s2pw  = (const float*)d_in[25];
  const float* s2pg  = (const float*)d_in[26];
  const float* s2pb  = (const float*)d_in[27];
  const float* s2tw  = (const float*)d_in[28];
  const float* s2tg  = (const float*)d_in[29];
  const float* s2tb  = (const float*)d_in[30];

  float* W = (float*)d_ws;
  float* Am  = W;            // 256
  float* sAv = W + 256;      // 16
  float* scA = W + 512;  float* shA = W + 640;
  float* scB = W + 768;  float* shB = W + 896;
  float* scC = W + 1024; float* shC = W + 1152;
  float* scD = W + 1280; float* shD = W + 1408;
  float* scE = W + 1536; float* shE = W + 1664;
  float* scG = W + 1792; float* shG = W + 1920;
  float* scF = W + 2048; float* shF = W + 4096;   // 2048 each
  float* scH = W + 6144; float* shH = W + 8192;   // ends 10240
  int*   cntA  = (int*)(W + 10240);               // 16
  int*   lvA   = (int*)(W + 10496);               // 256
  float* lvalA = W + 10752;                       // 256 -> ends 11008
  // BN accumulators + counters (zeroed each call via hipMemsetAsync)
  float* accZ1  = W + 11264;   // 256
  float* accZ2  = W + 11520;
  float* accZ3  = W + 11776;
  float* accZ4  = W + 12032;
  float* accS1P = W + 12288;
  float* accS2P = W + 12544;
  float* accS1T = W + 12800;   // 4096
  float* accS2T = W + 16896;   // 4096 -> ends 20992
  int*   cnts   = (int*)(W + 20992);  // 8 ints
  float* A = W + 24576;
  float* B = A + 16777216;
  float* C = B + 16777216;
  float* outp = (float*)d_out;

  unsigned short* A0 = (unsigned short*)A;
  unsigned short* A1 = (unsigned short*)(A + 8388608);
  unsigned short* B0 = (unsigned short*)B;
  unsigned short* B1 = (unsigned short*)(B + 8388608);
  unsigned short* C0 = (unsigned short*)C;
  unsigned short* C1 = (unsigned short*)(C + 8388608);

  // dynamic weights in d_out scratch (fully overwritten by maxdyn/maxstat later)
  unsigned short* OW = (unsigned short*)d_out;
  unsigned short* w_d1g = OW;
  unsigned short* w_d1t = OW + 16384;
  unsigned short* w_d2g = OW + 65536;
  unsigned short* w_d2t = OW + 81920;
  // static weights in B1 (B1 never used by tensors in this schedule)
  unsigned short* SW    = B1;
  unsigned short* w_s1p = SW;
  unsigned short* w_s1t = SW + 16384;
  unsigned short* w_s2p = SW + 802816;
  unsigned short* w_s2t = SW + 819200;

  const float iN  = 1.f/131072.f;
  const float iNg = 1.f/8192.f;

  // ---- zero BN accumulators + counters; setup; x convert ----
  hipMemsetAsync(W + 11264, 0, (20992 - 11264 + 8) * 4, stream);
  k_setup<<<6785, 256, 0, stream>>>(nv1, nv2, Am, sAv, cntA, lvA, lvalA,
                                    d1gw, d1tw, d2gw, d2tw, OW,
                                    s1pw, s1tw, s2pw, s2tw, SW);
  k_xcvt<<<2048, 256, 0, stream>>>(x, A0, A1);                          // A0=xB, A1=xS

  // ======== dynamic branch ========
  k_aggGconv<<<2048, 256, 0, stream>>>(A0, cntA, lvA, lvalA, w_d1g, B0, d1gb, sAv,
                                       accZ1, cnts+0, d1b1g, d1b1b, scA, shA, iN);   // B0=z1
  k_conv<128,16,3,0,1,0,1,1><<<1024, 256, 0, stream>>>(B0, w_d1t, C0, 4096, scA, shA,
                                       accZ2, cnts+1, d1b2g, d1b2b, scB, shB, iN);   // C0=z2
  k_combineAggGconv<<<2048, 256, 0, stream>>>(C0, A0, cntA, lvA, lvalA, scB, shB, w_d2g,
                                       B0, C1, d2gb, sAv,
                                       accZ3, cnts+2, d2b1g, d2b1b, scC, shC, iN);   // B0=r2, C1=z3
  k_conv<128,16,3,0,1,0,1,1><<<1024, 256, 0, stream>>>(C1, w_d2t, A0, 4096, scC, shC,
                                       accZ4, cnts+3, d2b2g, d2b2b, scD, shD, iN);   // A0=z4 (xB dead)
  k_maxdyn<<<512, 256, 0, stream>>>(A0, B0, scD, shD, outp);

  // ======== static branch (xS=A1; weights in B1) ========
  k_conv<128,0,1,0,0,0,0,1><<<1024, 256, 0, stream>>>(A1, w_s1p, C0, 256, nullptr, nullptr,
                                       accS1P, cnts+4, s1pg, s1pb, scE, shE, iN);
  k_conv<128,1,3,1,1,0,0,2><<<1024, 256, 0, stream>>>(C0, w_s1t, A1, 256, scE, shE,
                                       accS1T, cnts+5, s1tg, s1tb, scF, shF, iNg);   // A1 reused (xS dead)
  k_conv<128,0,1,0,1,1,0,1><<<1024, 256, 0, stream>>>(A1, w_s2p, C0, 256, scF, shF,
                                       accS2P, cnts+6, s2pg, s2pb, scG, shG, iN);
  k_conv<128,1,3,1,1,0,0,2><<<1024, 256, 0, stream>>>(C0, w_s2t, A1, 256, scG, shG,
                                       accS2T, cnts+7, s2tg, s2tb, scH, shH, iNg);
  k_maxstat<<<512, 256, 0, stream>>>(A1, scH, shH, outp);
}

// Round 13
// 706.562 us; speedup vs baseline: 1.6620x; 1.6620x over previous
//
#include <hip/hip_runtime.h>

#define EPSBN 1e-5f

typedef __attribute__((ext_vector_type(8))) __bf16 bf16x8;
typedef __attribute__((ext_vector_type(4))) float f32x4;
typedef __attribute__((ext_vector_type(8))) unsigned short us8;

__device__ inline unsigned short f2bf(float f) {
  __bf16 h = (__bf16)f;
  return __builtin_bit_cast(unsigned short, h);
}
__device__ inline float bf2f(unsigned short u) {
  __bf16 h = __builtin_bit_cast(__bf16, u);
  return (float)h;
}

// ---- last-block BN finalize over NBANK-banked accumulators. All threads call uniformly. ----
template<int NCH, int NBANK>
__device__ inline void bn_tail(float* acc, int* cnt, int nblk,
    const float* __restrict__ gamma, const float* __restrict__ beta,
    float* __restrict__ sc, float* __restrict__ sh, float invN, int tid) {
  __syncthreads();                       // all this block's atomicAdds issued
  __shared__ int lastFlag;
  if (tid == 0) {
    __threadfence();
    lastFlag = (atomicAdd(cnt, 1) == nblk - 1) ? 1 : 0;
  }
  __syncthreads();
  if (!lastFlag) return;
  __threadfence();
  for (int ch = tid; ch < NCH; ch += 256) {
    float s1 = 0.f, s2 = 0.f;
    #pragma unroll 4
    for (int b = 0; b < NBANK; ++b) {
      s1 += __hip_atomic_load(acc + b*2*NCH + ch,       __ATOMIC_RELAXED, __HIP_MEMORY_SCOPE_AGENT);
      s2 += __hip_atomic_load(acc + b*2*NCH + NCH + ch, __ATOMIC_RELAXED, __HIP_MEMORY_SCOPE_AGENT);
    }
    float mean = s1 * invN;
    float var  = s2 * invN - mean * mean;
    float s = gamma[ch] * rsqrtf(var + EPSBN);
    sc[ch] = s;
    sh[ch] = beta[ch] - mean * s;
  }
}

// ---------------- merged setup: weight converts (bf16) + adjacency ----------------
__device__ inline void cvt_cw_seg(const float* w, unsigned short* o, int lidx) {
  o[lidx] = f2bf(w[lidx]);
}
__device__ inline void cvt_tw_seg(const float* w, unsigned short* o, int lidx) {
  int oo = lidx / 384;
  int r = lidx - oo*384;
  int tap = r >> 7, c = r & 127;
  o[lidx] = f2bf(w[(oo*128 + c)*3 + tap]);
}
__global__ __launch_bounds__(256) void k_setup(
    const float* __restrict__ nv1, const float* __restrict__ nv2,
    float* __restrict__ A, float* __restrict__ sA,
    int* __restrict__ cntA, int* __restrict__ lvA, float* __restrict__ lvalA,
    const float* __restrict__ d1g, const float* __restrict__ d1t,
    const float* __restrict__ d2g, const float* __restrict__ d2t,
    unsigned short* __restrict__ O,
    const float* __restrict__ s1p, const float* __restrict__ s1t,
    const float* __restrict__ s2p, const float* __restrict__ s2t,
    unsigned short* __restrict__ S)
{
  int b = blockIdx.x, tid = threadIdx.x;
  if (b < 512) {
    if (b < 64)        cvt_cw_seg(d1g, O,          b*256 + tid);
    else if (b < 256)  cvt_tw_seg(d1t, O + 16384, (b-64)*256 + tid);
    else if (b < 320)  cvt_cw_seg(d2g, O + 65536, (b-256)*256 + tid);
    else               cvt_tw_seg(d2t, O + 81920, (b-320)*256 + tid);
    return;
  }
  if (b < 6784) {
    int sb = b - 512;
    if (sb < 64)        cvt_cw_seg(s1p, S,           sb*256 + tid);
    else if (sb < 3136) cvt_tw_seg(s1t, S + 16384,  (sb-64)*256 + tid);
    else if (sb < 3200) cvt_cw_seg(s2p, S + 802816, (sb-3136)*256 + tid);
    else                cvt_tw_seg(s2t, S + 819200, (sb-3200)*256 + tid);
    return;
  }
  // ---- adjacency (single block) ----
  __shared__ float M[16][16];
  int i = tid >> 4, j = tid & 15;
  float acc = 0.f;
  #pragma unroll
  for (int k = 0; k < 64; ++k) acc += nv1[i*64+k] * nv2[k*16+j];
  M[i][j] = fmaxf(acc, 0.f);
  __syncthreads();
  if (tid < 16) {
    float m = -1e30f;
    for (int c = 0; c < 16; ++c) m = fmaxf(m, M[tid][c]);
    float e[16]; float s = 0.f;
    for (int c = 0; c < 16; ++c) { e[c] = expf(M[tid][c] - m); s += e[c]; }
    float inv = 1.f / s;
    float t1 = -1e30f, t2 = -1e30f;
    for (int c = 0; c < 16; ++c) {
      float a = e[c] * inv; e[c] = a;
      if (a > t1) { t2 = t1; t1 = a; }
      else if (a > t2) t2 = a;
    }
    for (int c = 0; c < 16; ++c) {
      bool keep = (e[c] > (1.0f/16.0f)) && (e[c] > t2);
      M[tid][c] = keep ? e[c] : 0.f;
    }
  }
  __syncthreads();
  A[tid] = M[tid>>4][tid&15];
  if (tid < 16) {           // tid = w (column)
    float s = 0.f;
    int cnt = 0;
    for (int v = 0; v < 16; ++v) {
      float a = M[v][tid];
      s += a;
      if (a != 0.f) { lvA[tid*16 + cnt] = v; lvalA[tid*16 + cnt] = a; ++cnt; }
    }
    sA[tid] = s;
    cntA[tid] = cnt;
  }
}

// ---------------- x -> xB (pos-major bf16) + xS (static-layout bf16), one pass ----------------
__global__ __launch_bounds__(256) void k_xcvt(const float* __restrict__ x,
                                              unsigned short* __restrict__ xB,
                                              unsigned short* __restrict__ xS) {
  __shared__ float tl[64*128];
  int b = blockIdx.x; int n = b >> 6; int t0q = b & 63;
  int tid = threadIdx.x;
  const float* xb = x + (long)n*524288 + t0q*64;
  for (int idx = tid; idx < 2048; idx += 256) {
    int c = idx >> 4, q = idx & 15;
    float4 v = *(const float4*)(xb + (long)c*4096 + q*4);
    int cb = c >> 2, cl = c & 3;
    #pragma unroll
    for (int j = 0; j < 4; ++j)
      tl[(4*q+j)*128 + (((cb ^ q) & 31) << 2) + cl] = ((const float*)&v)[j];
  }
  __syncthreads();
  for (int idx = tid; idx < 1024; idx += 256) {
    int pos = idx >> 4, c8 = (idx & 15) << 3;
    int cb0 = c8 >> 2, cb1 = cb0 + 1, qp = pos >> 2;
    f32x4 v0 = *(const f32x4*)&tl[pos*128 + (((cb0 ^ qp) & 31) << 2)];
    f32x4 v1 = *(const f32x4*)&tl[pos*128 + (((cb1 ^ qp) & 31) << 2)];
    us8 pk;
    pk[0]=f2bf(v0.x); pk[1]=f2bf(v0.y); pk[2]=f2bf(v0.z); pk[3]=f2bf(v0.w);
    pk[4]=f2bf(v1.x); pk[5]=f2bf(v1.y); pk[6]=f2bf(v1.z); pk[7]=f2bf(v1.w);
    *(us8*)(xB + ((long)n*4096 + t0q*64 + pos)*128 + c8) = pk;
    int vv = pos & 15, tt = pos >> 4;
    *(us8*)(xS + ((long)(n*16+vv)*256 + t0q*4 + tt)*128 + c8) = pk;
  }
}

// ========== fused: sparse-agg(xB) gather -> MFMA gconv -> z1 + banked BN stats ==========
__global__ __launch_bounds__(256) void k_aggGconv(
    const unsigned short* __restrict__ xB,
    const int* __restrict__ cntA, const int* __restrict__ lvA, const float* __restrict__ lvalA,
    const unsigned short* __restrict__ Wb,
    unsigned short* __restrict__ out,
    const float* __restrict__ gb, const float* __restrict__ sAv,
    float* __restrict__ acc_g, int* __restrict__ cnt_g,
    const float* __restrict__ gamma, const float* __restrict__ beta,
    float* __restrict__ scO, float* __restrict__ shO, float invN)
{
  __shared__ __align__(16) unsigned short Th[64*128];
  __shared__ int cntS[16];
  __shared__ int lvS[256];
  __shared__ float lvalS[256];
  int b = blockIdx.x; int n = b >> 6; int off = (b & 63) << 6;
  int tid = threadIdx.x;
  if (tid < 16) cntS[tid] = cntA[tid];
  lvS[tid] = lvA[tid];
  lvalS[tid] = lvalA[tid];
  __syncthreads();
  const unsigned short* xbase = xB + ((long)n*4096 + off)*128;
  for (int idx = tid; idx < 1024; idx += 256) {
    int pos = idx >> 4, c8 = (idx & 15) << 3;
    int tt = pos >> 4, w = pos & 15;
    float s[8];
    #pragma unroll
    for (int k = 0; k < 8; ++k) s[k] = 0.f;
    int cw = cntS[w];
    for (int j = 0; j < cw; ++j) {
      int p = tt*16 + lvS[w*16 + j];
      float a = lvalS[w*16 + j];
      us8 raw = *(const us8*)(xbase + (long)p*128 + c8);
      #pragma unroll
      for (int k = 0; k < 8; ++k) s[k] += a * bf2f(raw[k]);
    }
    us8 pk;
    #pragma unroll
    for (int k = 0; k < 8; ++k) pk[k] = f2bf(s[k]);
    int byteoff = (pos << 8) + (c8 << 1);
    byteoff ^= ((pos & 7) << 4);
    *(us8*)((char*)Th + byteoff) = pk;
  }
  __syncthreads();
  int wv = tid >> 6, lane = tid & 63, l15 = lane & 15, lhi = lane >> 4;
  int o0 = wv << 5;
  f32x4 zz = {0.f,0.f,0.f,0.f};
  f32x4 acc[2][4];
  #pragma unroll
  for (int i = 0; i < 2; ++i)
    #pragma unroll
    for (int q = 0; q < 4; ++q) acc[i][q] = zz;
  const unsigned short* wr0 = Wb + (long)(o0 + l15)*128 + lhi*8;
  const unsigned short* wr1 = wr0 + 16*128;
  #pragma unroll
  for (int kk = 0; kk < 4; ++kk) {
    int kc = kk*32 + lhi*8;
    bf16x8 a0 = *(const bf16x8*)(wr0 + kk*32);
    bf16x8 a1 = *(const bf16x8*)(wr1 + kk*32);
    #pragma unroll
    for (int pf = 0; pf < 4; ++pf) {
      int row = pf*16 + l15;
      int byteoff = (row << 8) + (kc << 1);
      byteoff ^= ((row & 7) << 4);
      bf16x8 bh = *(const bf16x8*)((const char*)Th + byteoff);
      acc[0][pf] = __builtin_amdgcn_mfma_f32_16x16x32_bf16(a0, bh, acc[0][pf], 0, 0, 0);
      acc[1][pf] = __builtin_amdgcn_mfma_f32_16x16x32_bf16(a1, bh, acc[1][pf], 0, 0, 0);
    }
  }
  float s1a[2][4], s2a[2][4];
  #pragma unroll
  for (int i = 0; i < 2; ++i)
    #pragma unroll
    for (int j = 0; j < 4; ++j) { s1a[i][j] = 0.f; s2a[i][j] = 0.f; }
  unsigned short* og = out + ((long)n*4096 + off)*128;
  #pragma unroll
  for (int of = 0; of < 2; ++of) {
    int oc = o0 + of*16 + lhi*4;
    #pragma unroll
    for (int pf = 0; pf < 4; ++pf) {
      int pos = pf*16 + l15;
      f32x4 r = acc[of][pf];
      float s = sAv[l15];
      r.x += gb[oc+0]*s; r.y += gb[oc+1]*s;
      r.z += gb[oc+2]*s; r.w += gb[oc+3]*s;
      ushort4 pk;
      pk.x = f2bf(r.x); pk.y = f2bf(r.y); pk.z = f2bf(r.z); pk.w = f2bf(r.w);
      *(ushort4*)(og + (long)pos*128 + oc) = pk;
      #pragma unroll
      for (int j = 0; j < 4; ++j) { s1a[of][j] += r[j]; s2a[of][j] += r[j]*r[j]; }
    }
  }
  #pragma unroll
  for (int of = 0; of < 2; ++of)
    #pragma unroll
    for (int j = 0; j < 4; ++j) {
      float a = s1a[of][j], b2 = s2a[of][j];
      #pragma unroll
      for (int m = 1; m < 16; m <<= 1) { a += __shfl_xor(a, m); b2 += __shfl_xor(b2, m); }
      s1a[of][j] = a; s2a[of][j] = b2;
    }
  float* ab = acc_g + (long)(b & 31) * 256;     // 32 banks
  if (l15 == 0) {
    #pragma unroll
    for (int of = 0; of < 2; ++of)
      #pragma unroll
      for (int j = 0; j < 4; ++j) {
        int ch = o0 + of*16 + lhi*4 + j;
        atomicAdd(ab + ch, s1a[of][j]);
        atomicAdd(ab + 128 + ch, s2a[of][j]);
      }
  }
  bn_tail<128,32>(acc_g, cnt_g, gridDim.x, gamma, beta, scO, shO, invN, tid);
}

// ========== fused: r2=relu(bn(z2)+xB) -> bf16; sparse-agg; gconv2 -> z3 + banked BN stats ==========
__global__ __launch_bounds__(256) void k_combineAggGconv(
    const unsigned short* __restrict__ z, const unsigned short* __restrict__ xB,
    const int* __restrict__ cntA, const int* __restrict__ lvA, const float* __restrict__ lvalA,
    const float* __restrict__ sc, const float* __restrict__ sh,
    const unsigned short* __restrict__ Wb,
    unsigned short* __restrict__ r2, unsigned short* __restrict__ out,
    const float* __restrict__ gb, const float* __restrict__ sAv,
    float* __restrict__ acc_g, int* __restrict__ cnt_g,
    const float* __restrict__ gamma, const float* __restrict__ beta,
    float* __restrict__ scO, float* __restrict__ shO, float invN)
{
  __shared__ __align__(16) unsigned short rl[64*128];
  __shared__ __align__(16) unsigned short Th[64*128];
  __shared__ int cntS[16];
  __shared__ int lvS[256];
  __shared__ float lvalS[256];
  int b = blockIdx.x;
  int tid = threadIdx.x;
  if (tid < 16) cntS[tid] = cntA[tid];
  lvS[tid] = lvA[tid];
  lvalS[tid] = lvalA[tid];
  long zbase = (long)b * 8192;
  for (int idx = tid; idx < 1024; idx += 256) {
    int pos = idx >> 4, c8 = (idx & 15) << 3;
    us8 zr = *(const us8*)(z  + zbase + (long)pos*128 + c8);
    us8 xr = *(const us8*)(xB + zbase + (long)pos*128 + c8);
    us8 pr;
    #pragma unroll
    for (int k = 0; k < 8; ++k) {
      int cc = c8 + k;
      float v = bf2f(zr[k]) * sc[cc] + sh[cc] + bf2f(xr[k]);
      pr[k] = f2bf(fmaxf(v, 0.f));
    }
    *(us8*)(rl + pos*128 + c8) = pr;
    *(us8*)(r2 + zbase + (long)pos*128 + c8) = pr;
  }
  __syncthreads();
  for (int idx = tid; idx < 1024; idx += 256) {
    int pos = idx >> 4, c8 = (idx & 15) << 3;
    int tt = pos >> 4, w = pos & 15;
    float s[8];
    #pragma unroll
    for (int k = 0; k < 8; ++k) s[k] = 0.f;
    int cw = cntS[w];
    for (int j = 0; j < cw; ++j) {
      int p = tt*16 + lvS[w*16 + j];
      float a = lvalS[w*16 + j];
      us8 raw = *(const us8*)(rl + p*128 + c8);
      #pragma unroll
      for (int k = 0; k < 8; ++k) s[k] += a * bf2f(raw[k]);
    }
    us8 pk;
    #pragma unroll
    for (int k = 0; k < 8; ++k) pk[k] = f2bf(s[k]);
    int byteoff = (pos << 8) + (c8 << 1);
    byteoff ^= ((pos & 7) << 4);
    *(us8*)((char*)Th + byteoff) = pk;
  }
  __syncthreads();
  int wv = tid >> 6, lane = tid & 63, l15 = lane & 15, lhi = lane >> 4;
  int o0 = wv << 5;
  f32x4 zz = {0.f,0.f,0.f,0.f};
  f32x4 acc[2][4];
  #pragma unroll
  for (int i = 0; i < 2; ++i)
    #pragma unroll
    for (int q = 0; q < 4; ++q) acc[i][q] = zz;
  const unsigned short* wr0 = Wb + (long)(o0 + l15)*128 + lhi*8;
  const unsigned short* wr1 = wr0 + 16*128;
  #pragma unroll
  for (int kk = 0; kk < 4; ++kk) {
    int kc = kk*32 + lhi*8;
    bf16x8 a0 = *(const bf16x8*)(wr0 + kk*32);
    bf16x8 a1 = *(const bf16x8*)(wr1 + kk*32);
    #pragma unroll
    for (int pf = 0; pf < 4; ++pf) {
      int row = pf*16 + l15;
      int byteoff = (row << 8) + (kc << 1);
      byteoff ^= ((row & 7) << 4);
      bf16x8 bh = *(const bf16x8*)((const char*)Th + byteoff);
      acc[0][pf] = __builtin_amdgcn_mfma_f32_16x16x32_bf16(a0, bh, acc[0][pf], 0, 0, 0);
      acc[1][pf] = __builtin_amdgcn_mfma_f32_16x16x32_bf16(a1, bh, acc[1][pf], 0, 0, 0);
    }
  }
  float s1a[2][4], s2a[2][4];
  #pragma unroll
  for (int i = 0; i < 2; ++i)
    #pragma unroll
    for (int j = 0; j < 4; ++j) { s1a[i][j] = 0.f; s2a[i][j] = 0.f; }
  unsigned short* og = out + zbase;
  #pragma unroll
  for (int of = 0; of < 2; ++of) {
    int oc = o0 + of*16 + lhi*4;
    #pragma unroll
    for (int pf = 0; pf < 4; ++pf) {
      int pos = pf*16 + l15;
      f32x4 r = acc[of][pf];
      float s = sAv[l15];
      r.x += gb[oc+0]*s; r.y += gb[oc+1]*s;
      r.z += gb[oc+2]*s; r.w += gb[oc+3]*s;
      ushort4 pk;
      pk.x = f2bf(r.x); pk.y = f2bf(r.y); pk.z = f2bf(r.z); pk.w = f2bf(r.w);
      *(ushort4*)(og + (long)pos*128 + oc) = pk;
      #pragma unroll
      for (int j = 0; j < 4; ++j) { s1a[of][j] += r[j]; s2a[of][j] += r[j]*r[j]; }
    }
  }
  #pragma unroll
  for (int of = 0; of < 2; ++of)
    #pragma unroll
    for (int j = 0; j < 4; ++j) {
      float a = s1a[of][j], b2 = s2a[of][j];
      #pragma unroll
      for (int m = 1; m < 16; m <<= 1) { a += __shfl_xor(a, m); b2 += __shfl_xor(b2, m); }
      s1a[of][j] = a; s2a[of][j] = b2;
    }
  float* ab = acc_g + (long)(b & 31) * 256;     // 32 banks
  if (l15 == 0) {
    #pragma unroll
    for (int of = 0; of < 2; ++of)
      #pragma unroll
      for (int j = 0; j < 4; ++j) {
        int ch = o0 + of*16 + lhi*4 + j;
        atomicAdd(ab + ch, s1a[of][j]);
        atomicAdd(ab + 128 + ch, s2a[of][j]);
      }
  }
  bn_tail<128,32>(acc_g, cnt_g, gridDim.x, gamma, beta, scO, shO, invN, tid);
}

// ================= MFMA conv, bf16 in/out, coalesced stores, banked in-kernel BN finalize =================
// BNMODE: 1 = 128-channel stats (32 banks), 2 = 2048-channel grouped by v=g&15 (1 bank)
template<int POSB, int HALO, int TAPS, int GROUPED_W, int IN_BN, int GROUPED_BN, int RELU_IN, int BNMODE>
__global__ __launch_bounds__(256) void k_conv(
    const unsigned short* __restrict__ in, const unsigned short* __restrict__ Wb,
    unsigned short* __restrict__ out, int L,
    const float* __restrict__ isc, const float* __restrict__ ish,
    float* __restrict__ acc_g, int* __restrict__ cnt_g,
    const float* __restrict__ gamma, const float* __restrict__ beta,
    float* __restrict__ scO, float* __restrict__ shO, float invN)
{
  constexpr int TW = POSB + 2*HALO;
  constexpr int PF = POSB / 16;
  constexpr int KT = TAPS*128;
  constexpr int NCH = (BNMODE == 2) ? 2048 : 128;
  constexpr int NBANK = (BNMODE == 2) ? 1 : 32;
  __shared__ __align__(16) unsigned short Th[TW*128];
  int tid = threadIdx.x;
  int bpg = L / POSB;
  int g = blockIdx.x / bpg;
  int pos0 = (blockIdx.x - g*bpg) * POSB;
  const unsigned short* ing = in + (long)g*L*128;

  int cbase = (IN_BN && GROUPED_BN) ? ((g & 15) << 7) : 0;
  for (int idx = tid; idx < TW*16; idx += 256) {
    int row = idx >> 4;
    int c8 = (idx & 15) << 3;
    int gp = pos0 + row - HALO;
    us8 h = (us8)0;
    if (gp >= 0 && gp < L) {
      us8 raw = *(const us8*)(ing + (long)gp*128 + c8);
      if (IN_BN) {
        #pragma unroll
        for (int j = 0; j < 8; ++j) {
          int ci = cbase + c8 + j;
          float v = bf2f(raw[j]) * isc[ci] + ish[ci];
          if (RELU_IN) v = fmaxf(v, 0.f);
          h[j] = f2bf(v);
        }
      } else {
        h = raw;
      }
    }
    int byteoff = (row << 8) + (c8 << 1);
    byteoff ^= ((row & 7) << 4);
    *(us8*)((char*)Th + byteoff) = h;
  }
  __syncthreads();

  int wv = tid >> 6, lane = tid & 63, l15 = lane & 15, lhi = lane >> 4;
  int o0 = wv << 5;

  f32x4 zz = {0.f,0.f,0.f,0.f};
  f32x4 acc[2][PF];
  #pragma unroll
  for (int i = 0; i < 2; ++i)
    #pragma unroll
    for (int q = 0; q < PF; ++q) acc[i][q] = zz;

  const unsigned short* Wg = Wb + (GROUPED_W ? (long)(g & 15)*128*KT : 0);
  const unsigned short* wr0 = Wg + (long)(o0 + l15)*KT + lhi*8;
  const unsigned short* wr1 = wr0 + 16*KT;

  #pragma unroll
  for (int tap = 0; tap < TAPS; ++tap) {
    #pragma unroll
    for (int kk = 0; kk < 4; ++kk) {
      int kc = kk*32 + lhi*8;
      bf16x8 a0 = *(const bf16x8*)(wr0 + tap*128 + kk*32);
      bf16x8 a1 = *(const bf16x8*)(wr1 + tap*128 + kk*32);
      #pragma unroll
      for (int pf = 0; pf < PF; ++pf) {
        int row = pf*16 + l15 + tap*HALO;
        int byteoff = (row << 8) + (kc << 1);
        byteoff ^= ((row & 7) << 4);
        bf16x8 bh = *(const bf16x8*)((const char*)Th + byteoff);
        acc[0][pf] = __builtin_amdgcn_mfma_f32_16x16x32_bf16(a0, bh, acc[0][pf], 0, 0, 0);
        acc[1][pf] = __builtin_amdgcn_mfma_f32_16x16x32_bf16(a1, bh, acc[1][pf], 0, 0, 0);
      }
    }
  }

  // BN partial sums -> banked global atomics
  float s1a[2][4], s2a[2][4];
  #pragma unroll
  for (int i = 0; i < 2; ++i)
    #pragma unroll
    for (int j = 0; j < 4; ++j) { s1a[i][j] = 0.f; s2a[i][j] = 0.f; }
  #pragma unroll
  for (int of = 0; of < 2; ++of)
    #pragma unroll
    for (int pf = 0; pf < PF; ++pf) {
      f32x4 r = acc[of][pf];
      #pragma unroll
      for (int j = 0; j < 4; ++j) { s1a[of][j] += r[j]; s2a[of][j] += r[j]*r[j]; }
    }
  #pragma unroll
  for (int of = 0; of < 2; ++of)
    #pragma unroll
    for (int j = 0; j < 4; ++j) {
      float a = s1a[of][j], b2 = s2a[of][j];
      #pragma unroll
      for (int m = 1; m < 16; m <<= 1) { a += __shfl_xor(a, m); b2 += __shfl_xor(b2, m); }
      s1a[of][j] = a; s2a[of][j] = b2;
    }
  int chbase = (BNMODE == 2) ? ((g & 15) << 7) : 0;
  float* ab = acc_g + (long)(blockIdx.x & (NBANK-1)) * 2 * NCH;
  if (l15 == 0) {
    #pragma unroll
    for (int of = 0; of < 2; ++of)
      #pragma unroll
      for (int j = 0; j < 4; ++j) {
        int ch = chbase + o0 + of*16 + lhi*4 + j;
        atomicAdd(ab + ch, s1a[of][j]);
        atomicAdd(ab + NCH + ch, s2a[of][j]);
      }
  }

  // output tile -> Th (swizzled) -> coalesced global store
  __syncthreads();
  #pragma unroll
  for (int of = 0; of < 2; ++of) {
    int oc = o0 + of*16 + lhi*4;
    #pragma unroll
    for (int pf = 0; pf < PF; ++pf) {
      int pos = pf*16 + l15;
      f32x4 r = acc[of][pf];
      ushort4 pk;
      pk.x = f2bf(r.x); pk.y = f2bf(r.y); pk.z = f2bf(r.z); pk.w = f2bf(r.w);
      int byteoff = (pos << 8) + (oc << 1);
      byteoff ^= ((pos & 7) << 4);
      *(ushort4*)((char*)Th + byteoff) = pk;
    }
  }
  __syncthreads();
  unsigned short* og = out + ((long)g*L + pos0)*128;
  for (int idx = tid; idx < POSB*16; idx += 256) {
    int row = idx >> 4, c8 = (idx & 15) << 3;
    int byteoff = (row << 8) + (c8 << 1);
    byteoff ^= ((row & 7) << 4);
    us8 v = *(const us8*)((const char*)Th + byteoff);
    *(us8*)(og + (long)row*128 + c8) = v;
  }

  bn_tail<NCH,NBANK>(acc_g, cnt_g, gridDim.x, gamma, beta, scO, shO, invN, tid);
}

// ---------------- dynamic tail: out[n,c,v] = max_t relu(bn(z)+r2), bf16 inputs ----------------
__global__ __launch_bounds__(256) void k_maxdyn(
    const unsigned short* __restrict__ z, const unsigned short* __restrict__ res,
    const float* __restrict__ sc, const float* __restrict__ sh,
    float* __restrict__ outp)
{
  int b = blockIdx.x; int n = b >> 4, v = b & 15;
  int tid = threadIdx.x; int c = tid & 127, h = tid >> 7;
  const unsigned short* zb = z   + ((long)n*4096 + v)*128 + c;
  const unsigned short* rb = res + ((long)n*4096 + v)*128 + c;
  float s = sc[c], bb = sh[c];
  float m = 0.f;
  for (int t = h; t < 256; t += 2) {
    float val = bf2f(zb[(long)t*2048]) * s + bb + bf2f(rb[(long)t*2048]);
    m = fmaxf(m, val);
  }
  __shared__ float red[256];
  red[tid] = m;
  __syncthreads();
  if (tid < 128)
    outp[(long)n*4096 + c*32 + v] = fmaxf(fmaxf(red[tid], red[tid+128]), 0.f);
}

// ---------------- static tail: out[n,c,16+v] = max_s bn(z[(n,v)][s][c]), bf16 ----------------
__global__ __launch_bounds__(256) void k_maxstat(
    const unsigned short* __restrict__ z,
    const float* __restrict__ sc, const float* __restrict__ sh,
    float* __restrict__ outp)
{
  int b = blockIdx.x; int n = b >> 4, v = b & 15;
  int tid = threadIdx.x; int c = tid & 127, h = tid >> 7;
  const unsigned short* zb = z + (long)b*256*128 + c;
  float s = sc[v*128 + c], bb = sh[v*128 + c];
  float m = -1e30f;
  for (int t = h; t < 256; t += 2)
    m = fmaxf(m, bf2f(zb[t*128]) * s + bb);
  __shared__ float red[256];
  red[tid] = m;
  __syncthreads();
  if (tid < 128)
    outp[(long)n*4096 + c*32 + 16 + v] = fmaxf(red[tid], red[tid+128]);
}

extern "C" void kernel_launch(void* const* d_in, const int* in_sizes, int n_in,
                              void* d_out, int out_size, void* d_ws, size_t ws_size,
                              hipStream_t stream) {
  (void)in_sizes; (void)n_in; (void)out_size; (void)ws_size;
  const float* x     = (const float*)d_in[0];
  const float* nv1   = (const float*)d_in[1];
  const float* nv2   = (const float*)d_in[2];
  const float* d1gw  = (const float*)d_in[3];
  const float* d1gb  = (const float*)d_in[4];
  const float* d1b1g = (const float*)d_in[5];
  const float* d1b1b = (const float*)d_in[6];
  const float* d1tw  = (const float*)d_in[7];
  const float* d1b2g = (const float*)d_in[9];
  const float* d1b2b = (const float*)d_in[10];
  const float* d2gw  = (const float*)d_in[11];
  const float* d2gb  = (const float*)d_in[12];
  const float* d2b1g = (const float*)d_in[13];
  const float* d2b1b = (const float*)d_in[14];
  const float* d2tw  = (const float*)d_in[15];
  const float* d2b2g = (const float*)d_in[17];
  const float* d2b2b = (const float*)d_in[18];
  const float* s1pw  = (const float*)d_in[19];
  const float* s1pg  = (const float*)d_in[20];
  const float* s1pb  = (const float*)d_in[21];
  const float* s1tw  = (const float*)d_in[22];
  const float* s1tg  = (const float*)d_in[23];
  const float* s1tb  = (const float*)d_in[24];
  const float* s2pw  = (const float*)d_in[25];
  const float* s2pg  = (const float*)d_in[26];
  const float* s2pb  = (const float*)d_in[27];
  const float* s2tw  = (const float*)d_in[28];
  const float* s2tg  = (const float*)d_in[29];
  const float* s2tb  = (const float*)d_in[30];

  float* W = (float*)d_ws;
  float* Am  = W;            // 256
  float* sAv = W + 256;      // 16
  float* scA = W + 512;  float* shA = W + 640;
  float* scB = W + 768;  float* shB = W + 896;
  float* scC = W + 1024; float* shC = W + 1152;
  float* scD = W + 1280; float* shD = W + 1408;
  float* scE = W + 1536; float* shE = W + 1664;
  float* scG = W + 1792; float* shG = W + 1920;
  float* scF = W + 2048; float* shF = W + 4096;   // 2048 each
  float* scH = W + 6144; float* shH = W + 8192;   // ends 10240
  int*   cntA  = (int*)(W + 10240);               // 16
  int*   lvA   = (int*)(W + 10496);               // 256
  float* lvalA = W + 10752;                       // 256 -> ends 11008
  // banked BN accumulators + counters (zeroed each call via hipMemsetAsync)
  float* ACC = W + 16384;
  float* accZ1  = ACC;             // 32 banks x 256 = 8192
  float* accZ2  = ACC + 8192;
  float* accZ3  = ACC + 16384;
  float* accZ4  = ACC + 24576;
  float* accS1P = ACC + 32768;
  float* accS2P = ACC + 40960;
  float* accS1T = ACC + 49152;     // 1 bank x 4096
  float* accS2T = ACC + 53248;     // 4096 -> ends 57344
  int*   cnts   = (int*)(ACC + 57344);  // 8 ints
  float* A = W + 81920;
  float* B = A + 16777216;
  float* C = B + 16777216;
  float* outp = (float*)d_out;

  unsigned short* A0 = (unsigned short*)A;
  unsigned short* A1 = (unsigned short*)(A + 8388608);
  unsigned short* B0 = (unsigned short*)B;
  unsigned short* B1 = (unsigned short*)(B + 8388608);
  unsigned short* C0 = (unsigned short*)C;
  unsigned short* C1 = (unsigned short*)(C + 8388608);

  // dynamic weights in d_out scratch (fully overwritten by maxdyn/maxstat later)
  unsigned short* OW = (unsigned short*)d_out;
  unsigned short* w_d1g = OW;
  unsigned short* w_d1t = OW + 16384;
  unsigned short* w_d2g = OW + 65536;
  unsigned short* w_d2t = OW + 81920;
  // static weights in B1 (B1 never used by tensors in this schedule)
  unsigned short* SW    = B1;
  unsigned short* w_s1p = SW;
  unsigned short* w_s1t = SW + 16384;
  unsigned short* w_s2p = SW + 802816;
  unsigned short* w_s2t = SW + 819200;

  const float iN  = 1.f/131072.f;
  const float iNg = 1.f/8192.f;

  // ---- zero BN accumulators + counters; setup; x convert ----
  hipMemsetAsync(ACC, 0, (57344 + 8) * 4, stream);
  k_setup<<<6785, 256, 0, stream>>>(nv1, nv2, Am, sAv, cntA, lvA, lvalA,
                                    d1gw, d1tw, d2gw, d2tw, OW,
                                    s1pw, s1tw, s2pw, s2tw, SW);
  k_xcvt<<<2048, 256, 0, stream>>>(x, A0, A1);                          // A0=xB, A1=xS

  // ======== dynamic branch ========
  k_aggGconv<<<2048, 256, 0, stream>>>(A0, cntA, lvA, lvalA, w_d1g, B0, d1gb, sAv,
                                       accZ1, cnts+0, d1b1g, d1b1b, scA, shA, iN);   // B0=z1
  k_conv<128,16,3,0,1,0,1,1><<<1024, 256, 0, stream>>>(B0, w_d1t, C0, 4096, scA, shA,
                                       accZ2, cnts+1, d1b2g, d1b2b, scB, shB, iN);   // C0=z2
  k_combineAggGconv<<<2048, 256, 0, stream>>>(C0, A0, cntA, lvA, lvalA, scB, shB, w_d2g,
                                       B0, C1, d2gb, sAv,
                                       accZ3, cnts+2, d2b1g, d2b1b, scC, shC, iN);   // B0=r2, C1=z3
  k_conv<128,16,3,0,1,0,1,1><<<1024, 256, 0, stream>>>(C1, w_d2t, A0, 4096, scC, shC,
                                       accZ4, cnts+3, d2b2g, d2b2b, scD, shD, iN);   // A0=z4 (xB dead)
  k_maxdyn<<<512, 256, 0, stream>>>(A0, B0, scD, shD, outp);

  // ======== static branch (xS=A1; weights in B1) ========
  k_conv<128,0,1,0,0,0,0,1><<<1024, 256, 0, stream>>>(A1, w_s1p, C0, 256, nullptr, nullptr,
                                       accS1P, cnts+4, s1pg, s1pb, scE, shE, iN);
  k_conv<128,1,3,1,1,0,0,2><<<1024, 256, 0, stream>>>(C0, w_s1t, A1, 256, scE, shE,
                                       accS1T, cnts+5, s1tg, s1tb, scF, shF, iNg);   // A1 reused (xS dead)
  k_conv<128,0,1,0,1,1,0,1><<<1024, 256, 0, stream>>>(A1, w_s2p, C0, 256, scF, shF,
                                       accS2P, cnts+6, s2pg, s2pb, scG, shG, iN);
  k_conv<128,1,3,1,1,0,0,2><<<1024, 256, 0, stream>>>(C0, w_s2t, A1, 256, scG, shG,
                                       accS2T, cnts+7, s2tg, s2tb, scH, shH, iNg);
  k_maxstat<<<512, 256, 0, stream>>>(A1, scH, shH, outp);
}